// Round 12
// baseline (287.951 us; speedup 1.0000x reference)
//
#include <hip/hip_runtime.h>
#include <hip/hip_bf16.h>
#include <math.h>

// Problem constants
#define D_MODEL 256
#define DEPTH 2
#define D_INNER 512
#define D_STATE 16
#define D_CONV 4
#define DT_RANK 16
#define BATCH 2
#define SEQLEN 2048
#define MROWS (BATCH * SEQLEN)   // 4096

#define CCH 128   // chunks per batch-sequence
#define LCH 16    // rows per chunk

typedef __attribute__((ext_vector_type(8))) short bf16x8;
typedef __attribute__((ext_vector_type(4))) float f32x4;

__device__ __forceinline__ float silu(float v) {
    return v / (1.0f + __expf(-v));
}

__device__ __forceinline__ ushort f2bf(float f) {
    union { float f; unsigned u; } v; v.f = f;
    unsigned r = v.u + 0x7FFFu + ((v.u >> 16) & 1u);
    return (ushort)(r >> 16);
}

__device__ __forceinline__ float bf2f(ushort u) {
    union { unsigned u; float f; } v; v.u = ((unsigned)u) << 16;
    return v.f;
}

#define XS_STR 260   // f32 stride, 19-row LN tile
#define HS_STR 264   // ushort stride, 19-row bf16 LN output
#define XC_STR 520   // ushort stride, xc/yy LDS tiles (2-way conflicts max)

// ---------------------------------------------------------------------------
// k_cvt: all three weight tensors f32 -> bf16 in one dispatch (grid 512x256).
// ---------------------------------------------------------------------------
__global__ __launch_bounds__(256) void k_cvt(
    const float* __restrict__ ipw, const float* __restrict__ xpw,
    const float* __restrict__ opw, ushort* __restrict__ ipwB,
    ushort* __restrict__ xpwB, ushort* __restrict__ opwB)
{
    size_t tid = (size_t)blockIdx.x * 256 + threadIdx.x;
    {
        float4 v = ((const float4*)ipw)[tid];
        ushort4 o = { f2bf(v.x), f2bf(v.y), f2bf(v.z), f2bf(v.w) };
        ((ushort4*)ipwB)[tid] = o;
    }
    if (tid < 12288) {
        float4 v = ((const float4*)xpw)[tid];
        ushort4 o = { f2bf(v.x), f2bf(v.y), f2bf(v.z), f2bf(v.w) };
        ((ushort4*)xpwB)[tid] = o;
    }
    if (tid < 65536) {
        float4 v = ((const float4*)opw)[tid];
        ushort4 o = { f2bf(v.x), f2bf(v.y), f2bf(v.z), f2bf(v.w) };
        ((ushort4*)opwB)[tid] = o;
    }
}

// ---------------------------------------------------------------------------
// k_front: LN (19 rows incl. 3-row conv halo) + in_proj MFMA + conv + SiLU
//          + x_proj MFMA + scan_sum, per 16-row chunk. Grid 256 x 1024.
// 16 waves: in_proj halo tile (waves 8-15) runs concurrently with the main
// tile (waves 0-7); conv and scan_sum split across thread-halves.
// ---------------------------------------------------------------------------
__global__ __launch_bounds__(1024) void k_front(
    const float* __restrict__ xin, const float* __restrict__ lnwL,
    const float* __restrict__ lnbL, const ushort* __restrict__ ipwL,
    const float* __restrict__ cwL, const float* __restrict__ cbL,
    const ushort* __restrict__ xpwL, const float* __restrict__ dpwL,
    const float* __restrict__ dpbL, const float* __restrict__ alogL,
    ushort* __restrict__ zsB, ushort* __restrict__ xcB,
    float* __restrict__ dbl, float* __restrict__ Ssum,
    float* __restrict__ sdsum)
{
    const int t = threadIdx.x, bid = blockIdx.x;
    const int lane = t & 63, w = t >> 6, l15 = lane & 15, quad = lane >> 4;
    __shared__ float  xs[19 * XS_STR];     // 19.8 KB
    __shared__ ushort hs[19 * HS_STR];     // 10.0 KB
    __shared__ ushort xi_s[19 * 512];      // 19.5 KB  rows: m0-3 .. m0+15
    __shared__ ushort xc_s[16 * XC_STR];   // 16.6 KB
    __shared__ float  dbl_s[16 * 52];      //  3.3 KB
    int m0 = bid * 16;

    // ---- stage x rows m0-3 .. m0+15 (clamp row<0; batch masking via conv) --
    for (int i = t; i < 19 * 64; i += 1024) {
        int r = i >> 6, c = (i & 63) * 4;
        int grow = m0 - 3 + r; if (grow < 0) grow = 0;
        float4 v = *(const float4*)(xin + (size_t)grow * D_MODEL + c);
        *(float4*)&xs[r * XS_STR + c] = v;
    }
    __syncthreads();

    // ---- LayerNorm, 19 rows x 16 threads ----
    if (t < 19 * 16) {
        int r = t >> 4, ci = t & 15;
        float s = 0.f, sq = 0.f;
        #pragma unroll
        for (int k = 0; k < 16; k++) {
            float v = xs[r * XS_STR + ci + 16 * k];
            s += v; sq += v * v;
        }
        #pragma unroll
        for (int off = 1; off < 16; off <<= 1) {
            s  += __shfl_xor(s, off, 16);
            sq += __shfl_xor(sq, off, 16);
        }
        float mu  = s * (1.0f / 256.f);
        float var = sq * (1.0f / 256.f) - mu * mu;
        float rst = rsqrtf(var + 1e-5f);
        #pragma unroll
        for (int k = 0; k < 16; k++) {
            int c = ci + 16 * k;
            float v = (xs[r * XS_STR + c] - mu) * rst * lnwL[c] + lnbL[c];
            hs[r * HS_STR + c] = f2bf(v);
        }
    }
    __syncthreads();

    // ---- in_proj MFMA: waves 0-7 main tile (rows m0..m0+15, all n),
    //      waves 8-15 halo tile (rows m0-3..m0-1 kept, n<512). Concurrent. --
    if (w < 8) {
        #pragma unroll
        for (int f = 0; f < 8; f++) {
            int n = w * 128 + f * 16 + l15;
            f32x4 acc = (f32x4){0.f, 0.f, 0.f, 0.f};
            for (int k0 = 0; k0 < D_MODEL; k0 += 32) {
                bf16x8 af = *(const bf16x8*)&hs[(3 + l15) * HS_STR + quad * 8 + k0];
                bf16x8 bw = *(const bf16x8*)(ipwL + (size_t)n * D_MODEL + quad * 8 + k0);
                acc = __builtin_amdgcn_mfma_f32_16x16x32_bf16(af, bw, acc, 0, 0, 0);
            }
            #pragma unroll
            for (int r2 = 0; r2 < 4; r2++) {
                int rl = quad * 4 + r2;
                if (w < 4) xi_s[(3 + rl) * 512 + n] = f2bf(acc[r2]);
                else zsB[(size_t)(m0 + rl) * D_INNER + (n - 512)] = f2bf(silu(acc[r2]));
            }
        }
    } else {
        #pragma unroll
        for (int f = 0; f < 4; f++) {
            int n0 = (w - 8) * 64 + f * 16;
            f32x4 acc = (f32x4){0.f, 0.f, 0.f, 0.f};
            for (int k0 = 0; k0 < D_MODEL; k0 += 32) {
                bf16x8 af = *(const bf16x8*)&hs[l15 * HS_STR + quad * 8 + k0];
                bf16x8 bw = *(const bf16x8*)(ipwL + (size_t)(n0 + l15) * D_MODEL + quad * 8 + k0);
                acc = __builtin_amdgcn_mfma_f32_16x16x32_bf16(af, bw, acc, 0, 0, 0);
            }
            if (quad == 0) {
                #pragma unroll
                for (int r2 = 0; r2 < 3; r2++)
                    xi_s[r2 * 512 + n0 + l15] = f2bf(acc[r2]);
            }
        }
    }
    __syncthreads();

    // ---- conv(4) + SiLU -> xc_s + xcB. d = t&511, 8 rows per half ----
    {
        int d = t & 511, half = t >> 9;
        float4 cw4 = *(const float4*)(cwL + d * 4);
        float cbv = cbL[d];
        #pragma unroll
        for (int rr = 0; rr < 8; rr++) {
            int rl = half * 8 + rr;
            int l = (m0 + rl) & (SEQLEN - 1);
            float s = cbv;
            if (l >= 3) s = fmaf(cw4.x, bf2f(xi_s[(rl + 0) * 512 + d]), s);
            if (l >= 2) s = fmaf(cw4.y, bf2f(xi_s[(rl + 1) * 512 + d]), s);
            if (l >= 1) s = fmaf(cw4.z, bf2f(xi_s[(rl + 2) * 512 + d]), s);
            s = fmaf(cw4.w, bf2f(xi_s[(rl + 3) * 512 + d]), s);
            ushort xcv = f2bf(silu(s));
            xc_s[rl * XC_STR + d] = xcv;
            xcB[(size_t)(m0 + rl) * D_INNER + d] = xcv;
        }
    }
    __syncthreads();

    // ---- x_proj MFMA (waves 0..2, one 16-n tile each) ----
    if (w < 3) {
        f32x4 acc = (f32x4){0.f, 0.f, 0.f, 0.f};
        for (int k0 = 0; k0 < D_INNER; k0 += 32) {
            bf16x8 af = *(const bf16x8*)&xc_s[l15 * XC_STR + quad * 8 + k0];
            bf16x8 bw = *(const bf16x8*)(xpwL + (size_t)(w * 16 + l15) * D_INNER + quad * 8 + k0);
            acc = __builtin_amdgcn_mfma_f32_16x16x32_bf16(af, bw, acc, 0, 0, 0);
        }
        int n = w * 16 + l15;
        #pragma unroll
        for (int r2 = 0; r2 < 4; r2++) {
            int rl = quad * 4 + r2;
            dbl_s[rl * 52 + n] = acc[r2];
            dbl[(size_t)(m0 + rl) * 48 + n] = acc[r2];
        }
    }
    __syncthreads();

    // ---- scan_sum: d = t&511, states split across halves (8 each) ----
    {
        int d = t & 511, nh = t >> 9, nb = nh * 8;
        float a[8], wdp[16];
        #pragma unroll
        for (int k = 0; k < 8; k++) a[k] = -__expf(alogL[(size_t)d * 16 + nb + k]);
        *(float4*)&wdp[0]  = *(const float4*)(dpwL + (size_t)d * 16 + 0);
        *(float4*)&wdp[4]  = *(const float4*)(dpwL + (size_t)d * 16 + 4);
        *(float4*)&wdp[8]  = *(const float4*)(dpwL + (size_t)d * 16 + 8);
        *(float4*)&wdp[12] = *(const float4*)(dpwL + (size_t)d * 16 + 12);
        float bias = dpbL[d];
        float h[8];
        #pragma unroll
        for (int k = 0; k < 8; k++) h[k] = 0.f;
        float sd = 0.f;
        for (int j = 0; j < LCH; j++) {
            const float* dp = &dbl_s[j * 52];
            float dot = bias;
            #pragma unroll
            for (int r2 = 0; r2 < 16; r2++) dot = fmaf(dp[r2], wdp[r2], dot);
            float dl = (dot > 20.f) ? dot : log1pf(__expf(dot));
            float xv = bf2f(xc_s[j * XC_STR + d]);
            float u = dl * xv;
            sd += dl;
            #pragma unroll
            for (int k = 0; k < 8; k++)
                h[k] = fmaf(__expf(dl * a[k]), h[k], dp[16 + nb + k] * u);
        }
        size_t sbase = ((size_t)bid * 16) * D_INNER + d;
        #pragma unroll
        for (int k = 0; k < 8; k++)
            Ssum[sbase + (size_t)(nb + k) * D_INNER] = h[k];
        if (nh == 0) sdsum[(size_t)bid * D_INNER + d] = sd;
    }
}

// ---------------------------------------------------------------------------
// k_comb: in-place exclusive prefix over chunk summaries. Grid 64.
// ---------------------------------------------------------------------------
__global__ __launch_bounds__(256) void k_comb(
    const float* __restrict__ alogL, const float* __restrict__ sdsum,
    float* __restrict__ Ssum)
{
    const int t = threadIdx.x, bid = blockIdx.x;
    int dt2 = bid & 1;
    int n   = (bid >> 1) & 15;
    int b   = bid >> 5;
    int d   = dt2 * 256 + t;
    float a = -__expf(alogL[(size_t)d * 16 + n]);
    float hi = 0.f;
    #pragma unroll 4
    for (int c = 0; c < CCH; c++) {
        size_t idx = ((size_t)(b * CCH + c) * 16 + n) * D_INNER + d;
        float s  = Ssum[idx];
        float sd = sdsum[(size_t)(b * CCH + c) * D_INNER + d];
        Ssum[idx] = hi;
        hi = fmaf(__expf(a * sd), hi, s);
    }
}

// ---------------------------------------------------------------------------
// k_back: rescan (states split across halves, f32 partial y in LDS) +
//         D-skip + SiLU(z) gate + out_proj MFMA + residual. Grid 256 x 1024.
// ---------------------------------------------------------------------------
__global__ __launch_bounds__(1024) void k_back(
    const float* __restrict__ dbl, const ushort* __restrict__ xcB,
    const ushort* __restrict__ zsB, const float* __restrict__ Ssum,
    const float* __restrict__ dpwL, const float* __restrict__ dpbL,
    const float* __restrict__ alogL, const float* __restrict__ dparL,
    const ushort* __restrict__ opwL, const float* __restrict__ xin,
    float* __restrict__ xout)
{
    const int t = threadIdx.x, bid = blockIdx.x;
    const int lane = t & 63, w = t >> 6, l15 = lane & 15, quad = lane >> 4;
    __shared__ float  ypart[2 * 16 * 512];   // 64 KB
    __shared__ ushort yy_s[16 * XC_STR];     // 16.6 KB
    int m0 = bid * 16;

    // ---- rescan, d = t&511, 8 states per half ----
    {
        int d = t & 511, nh = t >> 9, nb = nh * 8;
        float a[8], wdp[16];
        #pragma unroll
        for (int k = 0; k < 8; k++) a[k] = -__expf(alogL[(size_t)d * 16 + nb + k]);
        *(float4*)&wdp[0]  = *(const float4*)(dpwL + (size_t)d * 16 + 0);
        *(float4*)&wdp[4]  = *(const float4*)(dpwL + (size_t)d * 16 + 4);
        *(float4*)&wdp[8]  = *(const float4*)(dpwL + (size_t)d * 16 + 8);
        *(float4*)&wdp[12] = *(const float4*)(dpwL + (size_t)d * 16 + 12);
        float bias = dpbL[d];
        float Dd = dparL[d];
        float h[8];
        size_t sbase = ((size_t)bid * 16) * D_INNER + d;
        #pragma unroll
        for (int k = 0; k < 8; k++)
            h[k] = Ssum[sbase + (size_t)(nb + k) * D_INNER];
        for (int j = 0; j < LCH; j++) {
            int row = m0 + j;
            const float* dp = dbl + (size_t)row * 48;
            float dtv[16], BCv[8];
            *(float4*)&dtv[0]  = *(const float4*)(dp + 0);
            *(float4*)&dtv[4]  = *(const float4*)(dp + 4);
            *(float4*)&dtv[8]  = *(const float4*)(dp + 8);
            *(float4*)&dtv[12] = *(const float4*)(dp + 12);
            *(float4*)&BCv[0]  = *(const float4*)(dp + 16 + nb + 0);
            *(float4*)&BCv[4]  = *(const float4*)(dp + 16 + nb + 4);
            float Cv[8];
            *(float4*)&Cv[0]   = *(const float4*)(dp + 32 + nb + 0);
            *(float4*)&Cv[4]   = *(const float4*)(dp + 32 + nb + 4);
            float dot = bias;
            #pragma unroll
            for (int r2 = 0; r2 < 16; r2++) dot = fmaf(dtv[r2], wdp[r2], dot);
            float dl = (dot > 20.f) ? dot : log1pf(__expf(dot));
            float xv = bf2f(xcB[(size_t)row * D_INNER + d]);
            float u = dl * xv;
            float y0 = 0.f, y1 = 0.f;
            #pragma unroll
            for (int k = 0; k < 8; k += 2) {
                h[k + 0] = fmaf(__expf(dl * a[k + 0]), h[k + 0], BCv[k + 0] * u);
                h[k + 1] = fmaf(__expf(dl * a[k + 1]), h[k + 1], BCv[k + 1] * u);
                y0 = fmaf(h[k + 0], Cv[k + 0], y0);
                y1 = fmaf(h[k + 1], Cv[k + 1], y1);
            }
            float y = y0 + y1;
            if (nh == 0) y += xv * Dd;
            ypart[nh * 8192 + j * 512 + d] = y;
        }
    }
    __syncthreads();

    // ---- combine halves + gate -> yy_s bf16 ----
    for (int e = t; e < 8192; e += 1024) {
        int j = e >> 9, d = e & 511;
        int row = m0 + j;
        float y = ypart[e] + ypart[8192 + e];
        yy_s[j * XC_STR + d] = f2bf(y * bf2f(zsB[(size_t)row * D_INNER + d]));
    }
    __syncthreads();

    // ---- out_proj MFMA + residual: 16 waves x one 16-n tile ----
    {
        int n = w * 16 + l15;
        f32x4 acc = (f32x4){0.f, 0.f, 0.f, 0.f};
        for (int k0 = 0; k0 < D_INNER; k0 += 32) {
            bf16x8 af = *(const bf16x8*)&yy_s[l15 * XC_STR + quad * 8 + k0];
            bf16x8 bw = *(const bf16x8*)(opwL + (size_t)n * D_INNER + quad * 8 + k0);
            acc = __builtin_amdgcn_mfma_f32_16x16x32_bf16(af, bw, acc, 0, 0, 0);
        }
        #pragma unroll
        for (int r2 = 0; r2 < 4; r2++) {
            int row = m0 + quad * 4 + r2;
            xout[(size_t)row * D_MODEL + n] =
                acc[r2] + xin[(size_t)row * D_MODEL + n];
        }
    }
}

// ---------------------------------------------------------------------------
// Launch
// ---------------------------------------------------------------------------
extern "C" void kernel_launch(void* const* d_in, const int* in_sizes, int n_in,
                              void* d_out, int out_size, void* d_ws, size_t ws_size,
                              hipStream_t stream)
{
    const float* x    = (const float*)d_in[0];
    const float* lnw  = (const float*)d_in[1];
    const float* lnb  = (const float*)d_in[2];
    const float* ipw  = (const float*)d_in[3];
    const float* cw   = (const float*)d_in[4];
    const float* cb   = (const float*)d_in[5];
    const float* xpw  = (const float*)d_in[6];
    const float* dpw  = (const float*)d_in[7];
    const float* dpb  = (const float*)d_in[8];
    const float* alog = (const float*)d_in[9];
    const float* dpar = (const float*)d_in[10];
    const float* opw  = (const float*)d_in[11];
    float* out = (float*)d_out;

    char* p = (char*)d_ws;
    auto alloc = [&](size_t bytes) { char* r = p; p += (bytes + 255) & ~(size_t)255; return r; };
    ushort* zsB   = (ushort*)alloc((size_t)MROWS * D_INNER * 2);
    ushort* xcB   = (ushort*)alloc((size_t)MROWS * D_INNER * 2);
    float*  dbl   = (float*)alloc((size_t)MROWS * 48 * 4);
    float*  Ssum  = (float*)alloc((size_t)BATCH * CCH * 16 * D_INNER * 4);
    float*  sdsum = (float*)alloc((size_t)BATCH * CCH * D_INNER * 4);
    float*  xbuf  = (float*)alloc((size_t)MROWS * D_MODEL * 4);
    ushort* ipwB  = (ushort*)alloc((size_t)DEPTH * 2 * D_INNER * D_MODEL * 2);
    ushort* xpwB  = (ushort*)alloc((size_t)DEPTH * 48 * D_INNER * 2);
    ushort* opwB  = (ushort*)alloc((size_t)DEPTH * D_MODEL * D_INNER * 2);

    k_cvt<<<512, 256, 0, stream>>>(ipw, xpw, opw, ipwB, xpwB, opwB);

    for (int lyr = 0; lyr < DEPTH; lyr++) {
        const float* xin = (lyr == 0) ? x : xbuf;
        float* xout = (lyr == DEPTH - 1) ? out : xbuf;
        const float* alogL = alog + (size_t)lyr * D_INNER * D_STATE;
        const float* dpwL  = dpw + (size_t)lyr * D_INNER * DT_RANK;
        const float* dpbL  = dpb + lyr * D_INNER;

        k_front<<<256, 1024, 0, stream>>>(
            xin, lnw + lyr * D_MODEL, lnb + lyr * D_MODEL,
            ipwB + (size_t)lyr * 2 * D_INNER * D_MODEL,
            cw + (size_t)lyr * D_INNER * D_CONV, cb + lyr * D_INNER,
            xpwB + (size_t)lyr * 48 * D_INNER, dpwL, dpbL, alogL,
            zsB, xcB, dbl, Ssum, sdsum);

        k_comb<<<64, 256, 0, stream>>>(alogL, sdsum, Ssum);

        k_back<<<256, 1024, 0, stream>>>(
            dbl, xcB, zsB, Ssum, dpwL, dpbL, alogL,
            dpar + lyr * D_INNER,
            opwB + (size_t)lyr * D_MODEL * D_INNER, xin, xout);
    }
}